// Round 5
// baseline (969.885 us; speedup 1.0000x reference)
//
#include <hip/hip_runtime.h>
#include <hip/hip_bf16.h>

#define FEAT 128

typedef __attribute__((ext_vector_type(8))) short short8;
typedef __attribute__((ext_vector_type(4))) float f32x4;

static __device__ __forceinline__ unsigned short f2bf(float f) {
    unsigned int u = __float_as_uint(f);
    unsigned int r = (u + 0x7fffu + ((u >> 16) & 1u)) >> 16;
    return (unsigned short)r;
}
static __device__ __forceinline__ float bf2f(unsigned short b) {
    return __uint_as_float(((unsigned int)b) << 16);
}

// ---- CSR build -------------------------------------------------------------

__global__ void hist_kernel(const int* __restrict__ dst, int* __restrict__ counts, int E) {
    int e = blockIdx.x * 256 + threadIdx.x;
    if (e < E) atomicAdd(&counts[dst[e]], 1);
}

__global__ __launch_bounds__(1024)
void scan_kernel(const int* __restrict__ counts, int* __restrict__ indptr,
                 int* __restrict__ cursor, float* __restrict__ dinv, int n, int E) {
    __shared__ int swave[16];
    __shared__ int s_carry;
    int tid = threadIdx.x, lane = tid & 63, wid = tid >> 6;
    if (tid == 0) s_carry = 0;
    __syncthreads();
    for (int base = 0; base < n; base += 4096) {
        int i4 = base + tid * 4;
        int4 v = {0, 0, 0, 0};
        if (i4 < n) v = *(const int4*)&counts[i4];
        int t = v.x + v.y + v.z + v.w;
        int x = t;
        #pragma unroll
        for (int off = 1; off < 64; off <<= 1) {
            int y = __shfl_up(x, off);
            if (lane >= off) x += y;
        }
        if (lane == 63) swave[wid] = x;
        __syncthreads();
        if (wid == 0 && lane < 16) {
            int s = swave[lane];
            #pragma unroll
            for (int off = 1; off < 16; off <<= 1) {
                int y = __shfl_up(s, off);
                if (lane >= off) s += y;
            }
            swave[lane] = s;
        }
        __syncthreads();
        int waveoff = (wid > 0) ? swave[wid - 1] : 0;
        int carry = s_carry;
        if (i4 < n) {
            int e0 = carry + waveoff + x - t;
            int p[4];
            p[0] = e0;
            p[1] = e0 + v.x;
            p[2] = p[1] + v.y;
            p[3] = p[2] + v.z;
            int c[4] = {v.x, v.y, v.z, v.w};
            #pragma unroll
            for (int j = 0; j < 4; ++j) {
                indptr[i4 + j] = p[j];
                cursor[i4 + j] = p[j];
                dinv[i4 + j]   = rsqrtf((float)(c[j] + 1));
            }
        }
        __syncthreads();
        if (tid == 1023) s_carry = carry + swave[15];
        __syncthreads();
    }
    if (threadIdx.x == 0) indptr[n] = E;
}

__global__ void fill_kernel(const int* __restrict__ src, const int* __restrict__ dst,
                            int* __restrict__ cursor, int* __restrict__ ssrc, int E) {
    int e = blockIdx.x * 256 + threadIdx.x;
    if (e < E) {
        int d = dst[e];
        int pos = atomicAdd(&cursor[d], 1);
        ssrc[pos] = src[e];
    }
}

// ---- bf16x2 split prep -----------------------------------------------------

// layer-0 activations: x fp32 -> (xh, xl) bf16 planes
__global__ void split_kernel(const float* __restrict__ in, unsigned short* __restrict__ xh,
                             unsigned short* __restrict__ xl, int total4) {
    int i = blockIdx.x * 256 + threadIdx.x;
    if (i >= total4) return;
    float4 v = ((const float4*)in)[i];
    ushort4 h, l;
    h.x = f2bf(v.x); l.x = f2bf(v.x - bf2f(h.x));
    h.y = f2bf(v.y); l.y = f2bf(v.y - bf2f(h.y));
    h.z = f2bf(v.z); l.z = f2bf(v.z - bf2f(h.z));
    h.w = f2bf(v.w); l.w = f2bf(v.w - bf2f(h.w));
    ((ushort4*)xh)[i] = h;
    ((ushort4*)xl)[i] = l;
}

// weights: Wt[l][n][k] = split(W_l[k][n])  (transposed for B-fragment loads)
__global__ void wprep_kernel(const float* __restrict__ W1, const float* __restrict__ W2,
                             const float* __restrict__ W3, unsigned short* __restrict__ wth,
                             unsigned short* __restrict__ wtl) {
    int idx = blockIdx.x * 256 + threadIdx.x;   // 3 * 16384
    int l = idx >> 14, t = idx & 16383;
    int nn = t >> 7, kk = t & 127;
    const float* W = (l == 0) ? W1 : (l == 1) ? W2 : W3;
    float v = W[kk * 128 + nn];
    unsigned short h = f2bf(v);
    wth[idx] = h;
    wtl[idx] = f2bf(v - bf2f(h));
}

// ---- GEMM (split-bf16 MFMA): hs[row] = (in[row] @ W) * dinv[row] -----------
// One wave per 16x16 tile; 4 waves/block share rows (A served from L1).
// 3 MFMAs per k-step emulate fp32: hi*hi + hi*lo + lo*hi (~17 mantissa bits).

__global__ __launch_bounds__(256)
void gemm_mfma(const unsigned short* __restrict__ xh, const unsigned short* __restrict__ xl,
               const unsigned short* __restrict__ wth, const unsigned short* __restrict__ wtl,
               const float* __restrict__ dinv, float* __restrict__ hs, int n) {
    int wave = threadIdx.x >> 6, lane = threadIdx.x & 63;
    int rowbase = blockIdx.x * 16;
    int colbase = blockIdx.y * 64 + wave * 16;
    int m  = lane & 15;          // A row / B col index within tile
    int kg = lane >> 4;          // k-group

    size_t aoff = (size_t)(rowbase + m) * FEAT + kg * 8;
    size_t boff = (size_t)(colbase + m) * FEAT + kg * 8;

    f32x4 acc = {0.f, 0.f, 0.f, 0.f};
    #pragma unroll
    for (int s = 0; s < 4; ++s) {            // K = 4 * 32
        short8 avh = *(const short8*)(xh  + aoff + s * 32);
        short8 avl = *(const short8*)(xl  + aoff + s * 32);
        short8 bvh = *(const short8*)(wth + boff + s * 32);
        short8 bvl = *(const short8*)(wtl + boff + s * 32);
        acc = __builtin_amdgcn_mfma_f32_16x16x32_bf16(avh, bvh, acc, 0, 0, 0);
        acc = __builtin_amdgcn_mfma_f32_16x16x32_bf16(avh, bvl, acc, 0, 0, 0);
        acc = __builtin_amdgcn_mfma_f32_16x16x32_bf16(avl, bvh, acc, 0, 0, 0);
    }

    int col = colbase + (lane & 15);
    int rb  = (lane >> 4) * 4;
    #pragma unroll
    for (int r = 0; r < 4; ++r) {
        int row = rowbase + rb + r;
        hs[(size_t)row * FEAT + col] = acc[r] * dinv[row];
    }
}

// ---- aggregation: out = act( dinv[i]*(hs[i] + sum hs[src]) + b ) -----------
// outf != null -> fp32 write (final layer); else write split bf16 planes.

__global__ __launch_bounds__(256)
void agg_kernel(const float* __restrict__ hs, const int* __restrict__ indptr,
                const int* __restrict__ ssrc, const float* __restrict__ dinv,
                const float* __restrict__ bias, float* __restrict__ outf,
                unsigned short* __restrict__ outh, unsigned short* __restrict__ outl,
                int n, int do_relu) {
    int wid = threadIdx.x >> 6, lane = threadIdx.x & 63;
    int node = blockIdx.x * 4 + wid;
    if (node >= n) return;

    const float2* hs2 = (const float2*)hs;
    float2 a0 = hs2[(size_t)node * 64 + lane];   // self-loop (pre-scaled by dinv[node])
    float2 a1 = {0.f, 0.f};

    int start = indptr[node], end = indptr[node + 1];
    for (int e0 = start; e0 < end; e0 += 64) {
        int cnt = end - e0;
        if (cnt > 64) cnt = 64;
        int sv = (lane < cnt) ? ssrc[e0 + lane] : 0;
        int j = 0;
        for (; j + 4 <= cnt; j += 4) {
            int s0 = __shfl(sv, j);
            int s1 = __shfl(sv, j + 1);
            int s2 = __shfl(sv, j + 2);
            int s3 = __shfl(sv, j + 3);
            float2 v0 = hs2[(size_t)s0 * 64 + lane];
            float2 v1 = hs2[(size_t)s1 * 64 + lane];
            float2 v2 = hs2[(size_t)s2 * 64 + lane];
            float2 v3 = hs2[(size_t)s3 * 64 + lane];
            a0.x += v0.x; a0.y += v0.y;
            a1.x += v1.x; a1.y += v1.y;
            a0.x += v2.x; a0.y += v2.y;
            a1.x += v3.x; a1.y += v3.y;
        }
        for (; j < cnt; ++j) {
            int s = __shfl(sv, j);
            float2 v = hs2[(size_t)s * 64 + lane];
            a0.x += v.x; a0.y += v.y;
        }
    }

    float d = dinv[node];
    float2 bv = ((const float2*)bias)[lane];
    float ox = (a0.x + a1.x) * d + bv.x;
    float oy = (a0.y + a1.y) * d + bv.y;
    if (do_relu) { ox = fmaxf(ox, 0.f); oy = fmaxf(oy, 0.f); }

    if (outf) {
        float2 o; o.x = ox; o.y = oy;
        ((float2*)outf)[(size_t)node * 64 + lane] = o;
    } else {
        ushort2 h, l;
        h.x = f2bf(ox); l.x = f2bf(ox - bf2f(h.x));
        h.y = f2bf(oy); l.y = f2bf(oy - bf2f(h.y));
        ((ushort2*)outh)[(size_t)node * 64 + lane] = h;
        ((ushort2*)outl)[(size_t)node * 64 + lane] = l;
    }
}

// ---- launch ----------------------------------------------------------------

static inline size_t align256(size_t x) { return (x + 255) & ~(size_t)255; }

extern "C" void kernel_launch(void* const* d_in, const int* in_sizes, int n_in,
                              void* d_out, int out_size, void* d_ws, size_t ws_size,
                              hipStream_t stream) {
    const float* x  = (const float*)d_in[0];
    const int*   ei = (const int*)d_in[1];
    const float* W1 = (const float*)d_in[2];
    const float* b1 = (const float*)d_in[3];
    const float* W2 = (const float*)d_in[4];
    const float* b2 = (const float*)d_in[5];
    const float* W3 = (const float*)d_in[6];
    const float* b3 = (const float*)d_in[7];

    int n = in_sizes[0] / FEAT;      // 100000
    int E = in_sizes[1] / 2;         // 1600000
    const int* src = ei;
    const int* dst = ei + E;

    // workspace carve-up (~60 MB)
    char* w = (char*)d_ws;
    int* counts  = (int*)w;                    w += align256((size_t)n * 4);
    int* indptr  = (int*)w;                    w += align256((size_t)(n + 1) * 4);
    int* cursor  = (int*)w;                    w += align256((size_t)n * 4);
    float* dinv  = (float*)w;                  w += align256((size_t)n * 4);
    int* ssrc    = (int*)w;                    w += align256((size_t)E * 4);
    float* hs    = (float*)w;                  w += align256((size_t)n * FEAT * 4);
    unsigned short* wth = (unsigned short*)w;  w += align256((size_t)3 * 16384 * 2);
    unsigned short* wtl = (unsigned short*)w;  w += align256((size_t)3 * 16384 * 2);

    // split activations live in d_out (exactly n*FEAT*4 bytes = two bf16 planes)
    unsigned short* xh = (unsigned short*)d_out;
    unsigned short* xl = xh + (size_t)n * FEAT;

    hipMemsetAsync(counts, 0, (size_t)n * 4, stream);

    hist_kernel<<<(E + 255) / 256, 256, 0, stream>>>(dst, counts, E);
    scan_kernel<<<1, 1024, 0, stream>>>(counts, indptr, cursor, dinv, n, E);
    fill_kernel<<<(E + 255) / 256, 256, 0, stream>>>(src, dst, cursor, ssrc, E);

    wprep_kernel<<<192, 256, 0, stream>>>(W1, W2, W3, wth, wtl);
    split_kernel<<<(n * FEAT / 4 + 255) / 256, 256, 0, stream>>>(x, xh, xl, n * FEAT / 4);

    for (int L = 0; L < 3; ++L) {
        const float* bb = (L == 0) ? b1 : (L == 1) ? b2 : b3;

        dim3 ggrid(n / 16, 2);
        gemm_mfma<<<ggrid, 256, 0, stream>>>(xh, xl, wth + (size_t)L * 16384,
                                             wtl + (size_t)L * 16384, dinv, hs, n);
        if (L < 2) {
            agg_kernel<<<(n + 3) / 4, 256, 0, stream>>>(hs, indptr, ssrc, dinv, bb,
                                                        nullptr, xh, xl, n, 1);
        } else {
            agg_kernel<<<(n + 3) / 4, 256, 0, stream>>>(hs, indptr, ssrc, dinv, bb,
                                                        (float*)d_out, nullptr, nullptr, n, 0);
        }
    }
}

// Round 6
// 896.637 us; speedup vs baseline: 1.0817x; 1.0817x over previous
//
#include <hip/hip_runtime.h>
#include <hip/hip_bf16.h>

#define FEAT 128

typedef __attribute__((ext_vector_type(8))) short short8;
typedef __attribute__((ext_vector_type(4))) float f32x4;

static __device__ __forceinline__ unsigned short f2bf(float f) {
    unsigned int u = __float_as_uint(f);
    unsigned int r = (u + 0x7fffu + ((u >> 16) & 1u)) >> 16;
    return (unsigned short)r;
}
static __device__ __forceinline__ float bf2f(unsigned short b) {
    return __uint_as_float(((unsigned int)b) << 16);
}

// ---- CSR build -------------------------------------------------------------
// 4 edges/thread: 4 independent atomic->store chains per thread (MLP), since
// round-4/5 showed fill latency-bound at 0.9 TB/s.

__global__ void hist_kernel(const int* __restrict__ dst, int* __restrict__ counts, int E) {
    int i = (blockIdx.x * 256 + threadIdx.x) * 4;
    if (i + 4 <= E) {
        int4 d4 = *(const int4*)(dst + i);
        atomicAdd(&counts[d4.x], 1);
        atomicAdd(&counts[d4.y], 1);
        atomicAdd(&counts[d4.z], 1);
        atomicAdd(&counts[d4.w], 1);
    } else {
        for (; i < E; ++i) atomicAdd(&counts[dst[i]], 1);
    }
}

__global__ __launch_bounds__(1024)
void scan_kernel(const int* __restrict__ counts, int* __restrict__ indptr,
                 int* __restrict__ cursor, float* __restrict__ dinv, int n, int E) {
    __shared__ int swave[16];
    __shared__ int s_carry;
    int tid = threadIdx.x, lane = tid & 63, wid = tid >> 6;
    if (tid == 0) s_carry = 0;
    __syncthreads();
    for (int base = 0; base < n; base += 4096) {
        int i4 = base + tid * 4;
        int4 v = {0, 0, 0, 0};
        if (i4 < n) v = *(const int4*)&counts[i4];
        int t = v.x + v.y + v.z + v.w;
        int x = t;
        #pragma unroll
        for (int off = 1; off < 64; off <<= 1) {
            int y = __shfl_up(x, off);
            if (lane >= off) x += y;
        }
        if (lane == 63) swave[wid] = x;
        __syncthreads();
        if (wid == 0 && lane < 16) {
            int s = swave[lane];
            #pragma unroll
            for (int off = 1; off < 16; off <<= 1) {
                int y = __shfl_up(s, off);
                if (lane >= off) s += y;
            }
            swave[lane] = s;
        }
        __syncthreads();
        int waveoff = (wid > 0) ? swave[wid - 1] : 0;
        int carry = s_carry;
        if (i4 < n) {
            int e0 = carry + waveoff + x - t;
            int p[4];
            p[0] = e0;
            p[1] = e0 + v.x;
            p[2] = p[1] + v.y;
            p[3] = p[2] + v.z;
            int c[4] = {v.x, v.y, v.z, v.w};
            #pragma unroll
            for (int j = 0; j < 4; ++j) {
                indptr[i4 + j] = p[j];
                cursor[i4 + j] = p[j];
                dinv[i4 + j]   = rsqrtf((float)(c[j] + 1));
            }
        }
        __syncthreads();
        if (tid == 1023) s_carry = carry + swave[15];
        __syncthreads();
    }
    if (threadIdx.x == 0) indptr[n] = E;
}

__global__ void fill_kernel(const int* __restrict__ src, const int* __restrict__ dst,
                            int* __restrict__ cursor, int* __restrict__ ssrc, int E) {
    int i = (blockIdx.x * 256 + threadIdx.x) * 4;
    if (i + 4 <= E) {
        int4 s4 = *(const int4*)(src + i);
        int4 d4 = *(const int4*)(dst + i);
        int p0 = atomicAdd(&cursor[d4.x], 1);
        int p1 = atomicAdd(&cursor[d4.y], 1);
        int p2 = atomicAdd(&cursor[d4.z], 1);
        int p3 = atomicAdd(&cursor[d4.w], 1);
        ssrc[p0] = s4.x;
        ssrc[p1] = s4.y;
        ssrc[p2] = s4.z;
        ssrc[p3] = s4.w;
    } else {
        for (; i < E; ++i) {
            int p = atomicAdd(&cursor[dst[i]], 1);
            ssrc[p] = src[i];
        }
    }
}

// ---- bf16x2 split prep -----------------------------------------------------

__global__ void split_kernel(const float* __restrict__ in, unsigned short* __restrict__ xh,
                             unsigned short* __restrict__ xl, int total4) {
    int i = blockIdx.x * 256 + threadIdx.x;
    if (i >= total4) return;
    float4 v = ((const float4*)in)[i];
    ushort4 h, l;
    h.x = f2bf(v.x); l.x = f2bf(v.x - bf2f(h.x));
    h.y = f2bf(v.y); l.y = f2bf(v.y - bf2f(h.y));
    h.z = f2bf(v.z); l.z = f2bf(v.z - bf2f(h.z));
    h.w = f2bf(v.w); l.w = f2bf(v.w - bf2f(h.w));
    ((ushort4*)xh)[i] = h;
    ((ushort4*)xl)[i] = l;
}

__global__ void wprep_kernel(const float* __restrict__ W1, const float* __restrict__ W2,
                             const float* __restrict__ W3, unsigned short* __restrict__ wth,
                             unsigned short* __restrict__ wtl) {
    int idx = blockIdx.x * 256 + threadIdx.x;   // 3 * 16384
    int l = idx >> 14, t = idx & 16383;
    int nn = t >> 7, kk = t & 127;
    const float* W = (l == 0) ? W1 : (l == 1) ? W2 : W3;
    float v = W[kk * 128 + nn];
    unsigned short h = f2bf(v);
    wth[idx] = h;
    wtl[idx] = f2bf(v - bf2f(h));
}

// ---- GEMM (split-bf16 MFMA): hs[row] = (in[row] @ W) * dinv[row] -----------
// One wave per 16-row strip x ALL 128 cols (8 tiles): A frags loaded once
// (32 VGPR), B streamed from the 64 KB L1/L2-resident planes, 96 MFMAs/wave.
// `#pragma unroll 2` on the tile loop: full unroll would hoist 64 B-loads and
// blow VGPRs (round-3 spill lesson).

__global__ __launch_bounds__(256)
void gemm_mfma(const unsigned short* __restrict__ xh, const unsigned short* __restrict__ xl,
               const unsigned short* __restrict__ wth, const unsigned short* __restrict__ wtl,
               const float* __restrict__ dinv, float* __restrict__ hs, int n) {
    const int wave = threadIdx.x >> 6, lane = threadIdx.x & 63;
    const int rowbase = blockIdx.x * 64 + wave * 16;
    const int m = lane & 15, kg = lane >> 4;

    int arow = rowbase + m;
    if (arow > n - 1) arow = n - 1;          // clamp; clamped rows are never stored
    const size_t aoff = (size_t)arow * FEAT + kg * 8;

    short8 avh[4], avl[4];
    #pragma unroll
    for (int s = 0; s < 4; ++s) {
        avh[s] = *(const short8*)(xh + aoff + s * 32);
        avl[s] = *(const short8*)(xl + aoff + s * 32);
    }

    f32x4 acc[8];
    #pragma unroll
    for (int t = 0; t < 8; ++t) acc[t] = (f32x4){0.f, 0.f, 0.f, 0.f};

    const size_t bbase = (size_t)m * FEAT + kg * 8;
    #pragma unroll 2
    for (int t = 0; t < 8; ++t) {
        const size_t boff = bbase + (size_t)t * 16 * FEAT;
        #pragma unroll
        for (int s = 0; s < 4; ++s) {
            short8 bvh = *(const short8*)(wth + boff + s * 32);
            short8 bvl = *(const short8*)(wtl + boff + s * 32);
            acc[t] = __builtin_amdgcn_mfma_f32_16x16x32_bf16(avh[s], bvh, acc[t], 0, 0, 0);
            acc[t] = __builtin_amdgcn_mfma_f32_16x16x32_bf16(avh[s], bvl, acc[t], 0, 0, 0);
            acc[t] = __builtin_amdgcn_mfma_f32_16x16x32_bf16(avl[s], bvh, acc[t], 0, 0, 0);
        }
    }

    const int col = lane & 15, rb = (lane >> 4) * 4;
    #pragma unroll
    for (int r = 0; r < 4; ++r) {
        int row = rowbase + rb + r;
        if (row < n) {
            float d = dinv[row];
            float* hrow = hs + (size_t)row * FEAT;
            #pragma unroll
            for (int t = 0; t < 8; ++t)
                hrow[t * 16 + col] = acc[t][r] * d;
        }
    }
}

// ---- aggregation: out = act( dinv[i]*(hs[i] + sum hs[src]) + b ) -----------

__global__ __launch_bounds__(256)
void agg_kernel(const float* __restrict__ hs, const int* __restrict__ indptr,
                const int* __restrict__ ssrc, const float* __restrict__ dinv,
                const float* __restrict__ bias, float* __restrict__ outf,
                unsigned short* __restrict__ outh, unsigned short* __restrict__ outl,
                int n, int do_relu) {
    int wid = threadIdx.x >> 6, lane = threadIdx.x & 63;
    int node = blockIdx.x * 4 + wid;
    if (node >= n) return;

    const float2* hs2 = (const float2*)hs;
    float2 a0 = hs2[(size_t)node * 64 + lane];   // self-loop (pre-scaled by dinv[node])
    float2 a1 = {0.f, 0.f};

    int start = indptr[node], end = indptr[node + 1];
    for (int e0 = start; e0 < end; e0 += 64) {
        int cnt = end - e0;
        if (cnt > 64) cnt = 64;
        int sv = (lane < cnt) ? ssrc[e0 + lane] : 0;
        int j = 0;
        for (; j + 4 <= cnt; j += 4) {
            int s0 = __shfl(sv, j);
            int s1 = __shfl(sv, j + 1);
            int s2 = __shfl(sv, j + 2);
            int s3 = __shfl(sv, j + 3);
            float2 v0 = hs2[(size_t)s0 * 64 + lane];
            float2 v1 = hs2[(size_t)s1 * 64 + lane];
            float2 v2 = hs2[(size_t)s2 * 64 + lane];
            float2 v3 = hs2[(size_t)s3 * 64 + lane];
            a0.x += v0.x; a0.y += v0.y;
            a1.x += v1.x; a1.y += v1.y;
            a0.x += v2.x; a0.y += v2.y;
            a1.x += v3.x; a1.y += v3.y;
        }
        for (; j < cnt; ++j) {
            int s = __shfl(sv, j);
            float2 v = hs2[(size_t)s * 64 + lane];
            a0.x += v.x; a0.y += v.y;
        }
    }

    float d = dinv[node];
    float2 bv = ((const float2*)bias)[lane];
    float ox = (a0.x + a1.x) * d + bv.x;
    float oy = (a0.y + a1.y) * d + bv.y;
    if (do_relu) { ox = fmaxf(ox, 0.f); oy = fmaxf(oy, 0.f); }

    if (outf) {
        float2 o; o.x = ox; o.y = oy;
        ((float2*)outf)[(size_t)node * 64 + lane] = o;
    } else {
        ushort2 h, l;
        h.x = f2bf(ox); l.x = f2bf(ox - bf2f(h.x));
        h.y = f2bf(oy); l.y = f2bf(oy - bf2f(h.y));
        ((ushort2*)outh)[(size_t)node * 64 + lane] = h;
        ((ushort2*)outl)[(size_t)node * 64 + lane] = l;
    }
}

// ---- launch ----------------------------------------------------------------

static inline size_t align256(size_t x) { return (x + 255) & ~(size_t)255; }

extern "C" void kernel_launch(void* const* d_in, const int* in_sizes, int n_in,
                              void* d_out, int out_size, void* d_ws, size_t ws_size,
                              hipStream_t stream) {
    const float* x  = (const float*)d_in[0];
    const int*   ei = (const int*)d_in[1];
    const float* W1 = (const float*)d_in[2];
    const float* b1 = (const float*)d_in[3];
    const float* W2 = (const float*)d_in[4];
    const float* b2 = (const float*)d_in[5];
    const float* W3 = (const float*)d_in[6];
    const float* b3 = (const float*)d_in[7];

    int n = in_sizes[0] / FEAT;      // 100000
    int E = in_sizes[1] / 2;         // 1600000
    const int* src = ei;
    const int* dst = ei + E;

    // workspace carve-up (~60 MB)
    char* w = (char*)d_ws;
    int* counts  = (int*)w;                    w += align256((size_t)n * 4);
    int* indptr  = (int*)w;                    w += align256((size_t)(n + 1) * 4);
    int* cursor  = (int*)w;                    w += align256((size_t)n * 4);
    float* dinv  = (float*)w;                  w += align256((size_t)n * 4);
    int* ssrc    = (int*)w;                    w += align256((size_t)E * 4);
    float* hs    = (float*)w;                  w += align256((size_t)n * FEAT * 4);
    unsigned short* wth = (unsigned short*)w;  w += align256((size_t)3 * 16384 * 2);
    unsigned short* wtl = (unsigned short*)w;  w += align256((size_t)3 * 16384 * 2);

    // split activations live in d_out (exactly n*FEAT*4 bytes = two bf16 planes)
    unsigned short* xh = (unsigned short*)d_out;
    unsigned short* xl = xh + (size_t)n * FEAT;

    hipMemsetAsync(counts, 0, (size_t)n * 4, stream);

    hist_kernel<<<(E / 4 + 255) / 256, 256, 0, stream>>>(dst, counts, E);
    scan_kernel<<<1, 1024, 0, stream>>>(counts, indptr, cursor, dinv, n, E);
    fill_kernel<<<(E / 4 + 255) / 256, 256, 0, stream>>>(src, dst, cursor, ssrc, E);

    wprep_kernel<<<192, 256, 0, stream>>>(W1, W2, W3, wth, wtl);
    split_kernel<<<(n * FEAT / 4 + 255) / 256, 256, 0, stream>>>(x, xh, xl, n * FEAT / 4);

    for (int L = 0; L < 3; ++L) {
        const float* bb = (L == 0) ? b1 : (L == 1) ? b2 : b3;

        gemm_mfma<<<(n + 63) / 64, 256, 0, stream>>>(xh, xl, wth + (size_t)L * 16384,
                                                     wtl + (size_t)L * 16384, dinv, hs, n);
        if (L < 2) {
            agg_kernel<<<(n + 3) / 4, 256, 0, stream>>>(hs, indptr, ssrc, dinv, bb,
                                                        nullptr, xh, xl, n, 1);
        } else {
            agg_kernel<<<(n + 3) / 4, 256, 0, stream>>>(hs, indptr, ssrc, dinv, bb,
                                                        (float*)d_out, nullptr, nullptr, n, 0);
        }
    }
}

// Round 8
// 637.460 us; speedup vs baseline: 1.5215x; 1.4066x over previous
//
#include <hip/hip_runtime.h>
#include <hip/hip_bf16.h>
#include <hip/hip_fp16.h>

#define FEAT 128

typedef __attribute__((ext_vector_type(8))) short short8;
typedef __attribute__((ext_vector_type(4))) float f32x4;

static __device__ __forceinline__ unsigned short f2bf(float f) {
    unsigned int u = __float_as_uint(f);
    unsigned int r = (u + 0x7fffu + ((u >> 16) & 1u)) >> 16;
    return (unsigned short)r;
}
static __device__ __forceinline__ float bf2f(unsigned short b) {
    return __uint_as_float(((unsigned int)b) << 16);
}

// ---- CSR build (round-4 forms: 1 edge/thread measured best) ----------------

__global__ void hist_kernel(const int* __restrict__ dst, int* __restrict__ counts, int E) {
    int e = blockIdx.x * 256 + threadIdx.x;
    if (e < E) atomicAdd(&counts[dst[e]], 1);
}

__global__ __launch_bounds__(1024)
void scan_kernel(const int* __restrict__ counts, int* __restrict__ indptr,
                 int* __restrict__ cursor, float* __restrict__ dinv, int n, int E) {
    __shared__ int swave[16];
    __shared__ int s_carry;
    int tid = threadIdx.x, lane = tid & 63, wid = tid >> 6;
    if (tid == 0) s_carry = 0;
    __syncthreads();
    for (int base = 0; base < n; base += 4096) {
        int i4 = base + tid * 4;
        int4 v = {0, 0, 0, 0};
        if (i4 < n) v = *(const int4*)&counts[i4];
        int t = v.x + v.y + v.z + v.w;
        int x = t;
        #pragma unroll
        for (int off = 1; off < 64; off <<= 1) {
            int y = __shfl_up(x, off);
            if (lane >= off) x += y;
        }
        if (lane == 63) swave[wid] = x;
        __syncthreads();
        if (wid == 0 && lane < 16) {
            int s = swave[lane];
            #pragma unroll
            for (int off = 1; off < 16; off <<= 1) {
                int y = __shfl_up(s, off);
                if (lane >= off) s += y;
            }
            swave[lane] = s;
        }
        __syncthreads();
        int waveoff = (wid > 0) ? swave[wid - 1] : 0;
        int carry = s_carry;
        if (i4 < n) {
            int e0 = carry + waveoff + x - t;
            int p[4];
            p[0] = e0;
            p[1] = e0 + v.x;
            p[2] = p[1] + v.y;
            p[3] = p[2] + v.z;
            int c[4] = {v.x, v.y, v.z, v.w};
            #pragma unroll
            for (int j = 0; j < 4; ++j) {
                indptr[i4 + j] = p[j];
                cursor[i4 + j] = p[j];
                dinv[i4 + j]   = rsqrtf((float)(c[j] + 1));
            }
        }
        __syncthreads();
        if (tid == 1023) s_carry = carry + swave[15];
        __syncthreads();
    }
    if (threadIdx.x == 0) indptr[n] = E;
}

__global__ void fill_kernel(const int* __restrict__ src, const int* __restrict__ dst,
                            int* __restrict__ cursor, int* __restrict__ ssrc, int E) {
    int e = blockIdx.x * 256 + threadIdx.x;
    if (e < E) {
        int d = dst[e];
        int pos = atomicAdd(&cursor[d], 1);
        ssrc[pos] = src[e];
    }
}

// ---- bf16x2 split prep -----------------------------------------------------

__global__ void split_kernel(const float* __restrict__ in, unsigned short* __restrict__ xh,
                             unsigned short* __restrict__ xl, int total4) {
    int i = blockIdx.x * 256 + threadIdx.x;
    if (i >= total4) return;
    float4 v = ((const float4*)in)[i];
    ushort4 h, l;
    h.x = f2bf(v.x); l.x = f2bf(v.x - bf2f(h.x));
    h.y = f2bf(v.y); l.y = f2bf(v.y - bf2f(h.y));
    h.z = f2bf(v.z); l.z = f2bf(v.z - bf2f(h.z));
    h.w = f2bf(v.w); l.w = f2bf(v.w - bf2f(h.w));
    ((ushort4*)xh)[i] = h;
    ((ushort4*)xl)[i] = l;
}

__global__ void wprep_kernel(const float* __restrict__ W1, const float* __restrict__ W2,
                             const float* __restrict__ W3, unsigned short* __restrict__ wth,
                             unsigned short* __restrict__ wtl) {
    int idx = blockIdx.x * 256 + threadIdx.x;   // 3 * 16384
    int l = idx >> 14, t = idx & 16383;
    int nn = t >> 7, kk = t & 127;
    const float* W = (l == 0) ? W1 : (l == 1) ? W2 : W3;
    float v = W[kk * 128 + nn];
    unsigned short h = f2bf(v);
    wth[idx] = h;
    wtl[idx] = f2bf(v - bf2f(h));
}

// ---- GEMM (split-bf16 MFMA, B staged in LDS): hs = (in @ W) * dinv, fp16 out
// Block = 4 waves = 64-row strip. B hi+lo planes (64 KB) staged once in LDS
// (row stride 136 shorts = 272 B -> 2-way bank aliasing = free per m136).
// ROUND-7 BUG FIXED: staging now writes 8 x short8 at stride 8 (full 64
// shorts per thread-half); round 7 wrote 4 at stride 16, leaving half of
// LDS uninitialized -> NaN.

__global__ __launch_bounds__(256)
void gemm_mfma(const unsigned short* __restrict__ xh, const unsigned short* __restrict__ xl,
               const unsigned short* __restrict__ wth, const unsigned short* __restrict__ wtl,
               const float* __restrict__ dinv, __half* __restrict__ hs, int n) {
    __shared__ unsigned short bh[128][136];
    __shared__ unsigned short bl[128][136];

    const int tid = threadIdx.x;
    const int wave = tid >> 6, lane = tid & 63;
    const int rowbase = blockIdx.x * 64 + wave * 16;
    const int m = lane & 15, kg = lane >> 4;

    // stage B: thread -> row n0 = tid>>1, half kk0 = (tid&1)*64
    {
        const int n0 = tid >> 1, kk0 = (tid & 1) * 64;
        const unsigned short* gh = wth + (size_t)n0 * FEAT + kk0;
        const unsigned short* gl = wtl + (size_t)n0 * FEAT + kk0;
        #pragma unroll
        for (int j = 0; j < 8; ++j) {
            *(short8*)&bh[n0][kk0 + j * 8] = *(const short8*)(gh + j * 8);
            *(short8*)&bl[n0][kk0 + j * 8] = *(const short8*)(gl + j * 8);
        }
    }

    // A fragments (loaded while staging is in flight)
    int arow = rowbase + m;
    if (arow > n - 1) arow = n - 1;          // clamp; clamped rows never stored
    const size_t aoff = (size_t)arow * FEAT + kg * 8;
    short8 avh[4], avl[4];
    #pragma unroll
    for (int s = 0; s < 4; ++s) {
        avh[s] = *(const short8*)(xh + aoff + s * 32);
        avl[s] = *(const short8*)(xl + aoff + s * 32);
    }

    __syncthreads();

    f32x4 acc[8];
    #pragma unroll
    for (int t = 0; t < 8; ++t) acc[t] = (f32x4){0.f, 0.f, 0.f, 0.f};

    #pragma unroll 2
    for (int t = 0; t < 8; ++t) {
        #pragma unroll
        for (int s = 0; s < 4; ++s) {
            short8 bvh = *(const short8*)&bh[t * 16 + m][s * 32 + kg * 8];
            short8 bvl = *(const short8*)&bl[t * 16 + m][s * 32 + kg * 8];
            acc[t] = __builtin_amdgcn_mfma_f32_16x16x32_bf16(avh[s], bvh, acc[t], 0, 0, 0);
            acc[t] = __builtin_amdgcn_mfma_f32_16x16x32_bf16(avh[s], bvl, acc[t], 0, 0, 0);
            acc[t] = __builtin_amdgcn_mfma_f32_16x16x32_bf16(avl[s], bvh, acc[t], 0, 0, 0);
        }
    }

    const int col = lane & 15, rb = (lane >> 4) * 4;
    #pragma unroll
    for (int r = 0; r < 4; ++r) {
        int row = rowbase + rb + r;
        if (row < n) {
            float d = dinv[row];
            __half* hrow = hs + (size_t)row * FEAT;
            #pragma unroll
            for (int t = 0; t < 8; ++t)
                hrow[t * 16 + col] = __float2half(acc[t][r] * d);
        }
    }
}

// ---- aggregation: out = act( dinv[i]*(hs[i] + sum hs[src]) + b ) -----------
// hs is fp16: gather is one __half2 per lane per edge (256 B/row).

__global__ __launch_bounds__(256)
void agg_kernel(const __half* __restrict__ hs, const int* __restrict__ indptr,
                const int* __restrict__ ssrc, const float* __restrict__ dinv,
                const float* __restrict__ bias, float* __restrict__ outf,
                unsigned short* __restrict__ outh, unsigned short* __restrict__ outl,
                int n, int do_relu) {
    int wid = threadIdx.x >> 6, lane = threadIdx.x & 63;
    int node = blockIdx.x * 4 + wid;
    if (node >= n) return;

    const __half2* hs2 = (const __half2*)hs;
    float2 a0 = __half22float2(hs2[(size_t)node * 64 + lane]);  // self-loop term
    float2 a1 = {0.f, 0.f};

    int start = indptr[node], end = indptr[node + 1];
    for (int e0 = start; e0 < end; e0 += 64) {
        int cnt = end - e0;
        if (cnt > 64) cnt = 64;
        int sv = (lane < cnt) ? ssrc[e0 + lane] : 0;
        int j = 0;
        for (; j + 4 <= cnt; j += 4) {
            int s0 = __shfl(sv, j);
            int s1 = __shfl(sv, j + 1);
            int s2 = __shfl(sv, j + 2);
            int s3 = __shfl(sv, j + 3);
            float2 v0 = __half22float2(hs2[(size_t)s0 * 64 + lane]);
            float2 v1 = __half22float2(hs2[(size_t)s1 * 64 + lane]);
            float2 v2 = __half22float2(hs2[(size_t)s2 * 64 + lane]);
            float2 v3 = __half22float2(hs2[(size_t)s3 * 64 + lane]);
            a0.x += v0.x; a0.y += v0.y;
            a1.x += v1.x; a1.y += v1.y;
            a0.x += v2.x; a0.y += v2.y;
            a1.x += v3.x; a1.y += v3.y;
        }
        for (; j < cnt; ++j) {
            int s = __shfl(sv, j);
            float2 v = __half22float2(hs2[(size_t)s * 64 + lane]);
            a0.x += v.x; a0.y += v.y;
        }
    }

    float d = dinv[node];
    float2 bv = ((const float2*)bias)[lane];
    float ox = (a0.x + a1.x) * d + bv.x;
    float oy = (a0.y + a1.y) * d + bv.y;
    if (do_relu) { ox = fmaxf(ox, 0.f); oy = fmaxf(oy, 0.f); }

    if (outf) {
        float2 o; o.x = ox; o.y = oy;
        ((float2*)outf)[(size_t)node * 64 + lane] = o;
    } else {
        ushort2 h, l;
        h.x = f2bf(ox); l.x = f2bf(ox - bf2f(h.x));
        h.y = f2bf(oy); l.y = f2bf(oy - bf2f(h.y));
        ((ushort2*)outh)[(size_t)node * 64 + lane] = h;
        ((ushort2*)outl)[(size_t)node * 64 + lane] = l;
    }
}

// ---- launch ----------------------------------------------------------------

static inline size_t align256(size_t x) { return (x + 255) & ~(size_t)255; }

extern "C" void kernel_launch(void* const* d_in, const int* in_sizes, int n_in,
                              void* d_out, int out_size, void* d_ws, size_t ws_size,
                              hipStream_t stream) {
    const float* x  = (const float*)d_in[0];
    const int*   ei = (const int*)d_in[1];
    const float* W1 = (const float*)d_in[2];
    const float* b1 = (const float*)d_in[3];
    const float* W2 = (const float*)d_in[4];
    const float* b2 = (const float*)d_in[5];
    const float* W3 = (const float*)d_in[6];
    const float* b3 = (const float*)d_in[7];

    int n = in_sizes[0] / FEAT;      // 100000
    int E = in_sizes[1] / 2;         // 1600000
    const int* src = ei;
    const int* dst = ei + E;

    // workspace carve-up (~35 MB)
    char* w = (char*)d_ws;
    int* counts  = (int*)w;                    w += align256((size_t)n * 4);
    int* indptr  = (int*)w;                    w += align256((size_t)(n + 1) * 4);
    int* cursor  = (int*)w;                    w += align256((size_t)n * 4);
    float* dinv  = (float*)w;                  w += align256((size_t)n * 4);
    int* ssrc    = (int*)w;                    w += align256((size_t)E * 4);
    __half* hs   = (__half*)w;                 w += align256((size_t)n * FEAT * 2);
    unsigned short* wth = (unsigned short*)w;  w += align256((size_t)3 * 16384 * 2);
    unsigned short* wtl = (unsigned short*)w;  w += align256((size_t)3 * 16384 * 2);

    // split activations live in d_out (exactly n*FEAT*4 bytes = two bf16 planes)
    unsigned short* xh = (unsigned short*)d_out;
    unsigned short* xl = xh + (size_t)n * FEAT;

    hipMemsetAsync(counts, 0, (size_t)n * 4, stream);

    hist_kernel<<<(E + 255) / 256, 256, 0, stream>>>(dst, counts, E);
    scan_kernel<<<1, 1024, 0, stream>>>(counts, indptr, cursor, dinv, n, E);
    fill_kernel<<<(E + 255) / 256, 256, 0, stream>>>(src, dst, cursor, ssrc, E);

    wprep_kernel<<<192, 256, 0, stream>>>(W1, W2, W3, wth, wtl);
    split_kernel<<<(n * FEAT / 4 + 255) / 256, 256, 0, stream>>>(x, xh, xl, n * FEAT / 4);

    for (int L = 0; L < 3; ++L) {
        const float* bb = (L == 0) ? b1 : (L == 1) ? b2 : b3;

        gemm_mfma<<<(n + 63) / 64, 256, 0, stream>>>(xh, xl, wth + (size_t)L * 16384,
                                                     wtl + (size_t)L * 16384, dinv, hs, n);
        if (L < 2) {
            agg_kernel<<<(n + 3) / 4, 256, 0, stream>>>(hs, indptr, ssrc, dinv, bb,
                                                        nullptr, xh, xl, n, 1);
        } else {
            agg_kernel<<<(n + 3) / 4, 256, 0, stream>>>(hs, indptr, ssrc, dinv, bb,
                                                        (float*)d_out, nullptr, nullptr, n, 0);
        }
    }
}